// Round 1
// baseline (191.290 us; speedup 1.0000x reference)
//
#include <hip/hip_runtime.h>
#include <hip/hip_bf16.h>

// Problem constants (from reference)
#define B_     64
#define NT_    64
#define WIN_   31
#define P_     (WIN_ * WIN_)   // 961
#define H_     512
#define W_     512

// out: (B, 2, NT, WIN, WIN, 1) float32
// imgs: (B, 2, H, W, 1) float32
// track_locs: (B, NT*2) float32

__global__ __launch_bounds__(256)
void motion_sample_kernel(const float* __restrict__ track_locs,
                          const float* __restrict__ imgs,
                          float* __restrict__ out) {
    // one block per (b, f, t)
    const int blk = blockIdx.x;          // 0 .. B*2*NT-1
    const int t = blk % NT_;
    const int f = (blk / NT_) & 1;
    const int b = blk / (NT_ * 2);

    const float scale = (float)WIN_ / (float)W_;       // 31/512
    const float tx = track_locs[b * (NT_ * 2) + 2 * t];
    const float ty = track_locs[b * (NT_ * 2) + 2 * t + 1];

    // x = (lin[j] + tx/scale) * (WIN*0.5); lin[j] = -1 + j*(2/30)
    const float halfwin = (float)WIN_ * 0.5f;          // 15.5
    const float basex = (-1.0f + tx / scale) * halfwin;
    const float basey = (-1.0f + ty / scale) * halfwin;
    const float step  = (2.0f / (float)(WIN_ - 1)) * halfwin;  // (2/30)*15.5

    const float* frame = imgs + (size_t)(b * 2 + f) * (H_ * W_);
    float* outp = out + (size_t)blk * P_;

    for (int p = threadIdx.x; p < P_; p += blockDim.x) {
        const int i = p / WIN_;     // row (y)
        const int j = p % WIN_;     // col (x)

        const float x = basex + (float)j * step;
        const float y = basey + (float)i * step;

        const float fx = floorf(x);
        const float fy = floorf(y);

        // clip on floats (reference clips float coords, then casts)
        const float x0f = fminf(fmaxf(fx,        0.0f), (float)(W_ - 1));
        const float x1f = fminf(fmaxf(fx + 1.0f, 0.0f), (float)(W_ - 1));
        const float y0f = fminf(fmaxf(fy,        0.0f), (float)(H_ - 1));
        const float y1f = fminf(fmaxf(fy + 1.0f, 0.0f), (float)(H_ - 1));

        const float wa = (y1f - y) * (x1f - x);
        const float wb = (y1f - y) * (x - x0f);
        const float wc = (y - y0f) * (x1f - x);
        const float wd = (y - y0f) * (x - x0f);

        const int x0i = (int)x0f;
        const int x1i = (int)x1f;
        const int y0i = (int)y0f;
        const int y1i = (int)y1f;

        const float Ia = frame[y0i * W_ + x0i];
        const float Ib = frame[y0i * W_ + x1i];
        const float Ic = frame[y1i * W_ + x0i];
        const float Id = frame[y1i * W_ + x1i];

        outp[p] = wa * Ia + wb * Ib + wc * Ic + wd * Id;
    }
}

extern "C" void kernel_launch(void* const* d_in, const int* in_sizes, int n_in,
                              void* d_out, int out_size, void* d_ws, size_t ws_size,
                              hipStream_t stream) {
    const float* track_locs = (const float*)d_in[0];   // (64, 128)
    const float* imgs       = (const float*)d_in[1];   // (64, 2, 512, 512, 1)
    float* out              = (float*)d_out;           // (64, 2, 64, 31, 31, 1)

    const int nblocks = B_ * 2 * NT_;   // 8192
    motion_sample_kernel<<<nblocks, 256, 0, stream>>>(track_locs, imgs, out);
}

// Round 2
// 185.938 us; speedup vs baseline: 1.0288x; 1.0288x over previous
//
#include <hip/hip_runtime.h>
#include <hip/hip_bf16.h>

// Problem constants (from reference)
#define B_     64
#define NT_    64
#define WIN_   31
#define P_     (WIN_ * WIN_)   // 961
#define H_     512
#define W_     512
#define TW_    34              // staged tile width/height (covers floor span 33 + pad)
#define TELEMS (TW_ * TW_)     // 1156

// out: (B, 2, NT, WIN, WIN, 1) float32
// imgs: (B, 2, H, W, 1) float32
// track_locs: (B, NT*2) float32

__global__ __launch_bounds__(256)
void motion_sample_kernel(const float* __restrict__ track_locs,
                          const float* __restrict__ imgs,
                          float* __restrict__ out) {
    // one block per (b, t); handles BOTH frames (shared coords/weights)
    const int blk = blockIdx.x;          // 0 .. B*NT-1
    const int t = blk % NT_;
    const int b = blk / NT_;

    const float scale = (float)WIN_ / (float)W_;       // 31/512
    const float tx = track_locs[b * (NT_ * 2) + 2 * t];
    const float ty = track_locs[b * (NT_ * 2) + 2 * t + 1];

    const float halfwin = (float)WIN_ * 0.5f;          // 15.5
    const float basex = (-1.0f + tx / scale) * halfwin;
    const float basey = (-1.0f + ty / scale) * halfwin;
    const float step  = (2.0f / (float)(WIN_ - 1)) * halfwin;  // 31/30

    const int xstart = (int)floorf(basex);   // >= -16
    const int ystart = (int)floorf(basey);

    __shared__ float tile0[TELEMS];
    __shared__ float tile1[TELEMS];

    const float* frame0 = imgs + (size_t)(b * 2 + 0) * (H_ * W_);
    const float* frame1 = imgs + (size_t)(b * 2 + 1) * (H_ * W_);

    // Stage 34x34 region of both frames, edge-clamped, coalesced along rows.
    for (int idx = threadIdx.x; idx < TELEMS; idx += 256) {
        const int r = idx / TW_;
        const int c = idx % TW_;
        const int gy = min(max(ystart + r, 0), H_ - 1);
        const int gx = min(max(xstart + c, 0), W_ - 1);
        const int g = gy * W_ + gx;
        tile0[idx] = frame0[g];
        tile1[idx] = frame1[g];
    }
    __syncthreads();

    float* out0 = out + (size_t)((b * 2 + 0) * NT_ + t) * P_;
    float* out1 = out + (size_t)((b * 2 + 1) * NT_ + t) * P_;

    for (int p = threadIdx.x; p < P_; p += 256) {
        const int i = p / WIN_;     // row (y)
        const int j = p % WIN_;     // col (x)

        const float x = basex + (float)j * step;
        const float y = basey + (float)i * step;

        const float fx = floorf(x);
        const float fy = floorf(y);

        // clip on floats (reference clips float coords, then casts)
        const float x0f = fminf(fmaxf(fx,        0.0f), (float)(W_ - 1));
        const float x1f = fminf(fmaxf(fx + 1.0f, 0.0f), (float)(W_ - 1));
        const float y0f = fminf(fmaxf(fy,        0.0f), (float)(H_ - 1));
        const float y1f = fminf(fmaxf(fy + 1.0f, 0.0f), (float)(H_ - 1));

        const float wa = (y1f - y) * (x1f - x);
        const float wb = (y1f - y) * (x - x0f);
        const float wc = (y - y0f) * (x1f - x);
        const float wd = (y - y0f) * (x - x0f);

        // local tile indices (clamped global index minus tile origin; in-range by construction)
        const int lx0 = (int)x0f - xstart;
        const int lx1 = (int)x1f - xstart;
        const int ly0 = (int)y0f - ystart;
        const int ly1 = (int)y1f - ystart;

        const int a00 = ly0 * TW_ + lx0;
        const int a01 = ly0 * TW_ + lx1;
        const int a10 = ly1 * TW_ + lx0;
        const int a11 = ly1 * TW_ + lx1;

        const float r0 = wa * tile0[a00] + wb * tile0[a01] + wc * tile0[a10] + wd * tile0[a11];
        const float r1 = wa * tile1[a00] + wb * tile1[a01] + wc * tile1[a10] + wd * tile1[a11];

        out0[p] = r0;
        out1[p] = r1;
    }
}

extern "C" void kernel_launch(void* const* d_in, const int* in_sizes, int n_in,
                              void* d_out, int out_size, void* d_ws, size_t ws_size,
                              hipStream_t stream) {
    const float* track_locs = (const float*)d_in[0];   // (64, 128)
    const float* imgs       = (const float*)d_in[1];   // (64, 2, 512, 512, 1)
    float* out              = (float*)d_out;           // (64, 2, 64, 31, 31, 1)

    const int nblocks = B_ * NT_;   // 4096
    motion_sample_kernel<<<nblocks, 256, 0, stream>>>(track_locs, imgs, out);
}

// Round 3
// 184.289 us; speedup vs baseline: 1.0380x; 1.0089x over previous
//
#include <hip/hip_runtime.h>
#include <hip/hip_bf16.h>

// Problem constants (from reference)
#define B_     64
#define NT_    64
#define WIN_   31
#define P_     (WIN_ * WIN_)   // 961
#define H_     512
#define W_     512
#define TW_    34              // staged tile width/height (covers floor span 33 + x1 overhang)
#define TELEMS (TW_ * TW_)     // 1156

// out: (B, 2, NT, WIN, WIN, 1) float32
// imgs: (B, 2, H, W, 1) float32
// track_locs: (B, NT*2) float32

__global__ __launch_bounds__(256)
void motion_sample_kernel(const float* __restrict__ track_locs,
                          const float* __restrict__ imgs,
                          float* __restrict__ out) {
    // one block per (b, t); handles BOTH frames (shared coords/weights)
    const int blk = blockIdx.x;          // 0 .. B*NT-1
    const int t = blk % NT_;
    const int b = blk / NT_;

    const float scale = (float)WIN_ / (float)W_;       // 31/512
    const float tx = track_locs[b * (NT_ * 2) + 2 * t];
    const float ty = track_locs[b * (NT_ * 2) + 2 * t + 1];

    const float halfwin = (float)WIN_ * 0.5f;          // 15.5
    const float basex = (-1.0f + tx / scale) * halfwin;
    const float basey = (-1.0f + ty / scale) * halfwin;
    const float step  = (2.0f / (float)(WIN_ - 1)) * halfwin;  // 31/30

    const int xstart = (int)floorf(basex);   // in [-16, 240]
    const int ystart = (int)floorf(basey);

    __shared__ float tile0[TELEMS];
    __shared__ float tile1[TELEMS];

    const float* frame0 = imgs + (size_t)(b * 2 + 0) * (H_ * W_);
    const float* frame1 = imgs + (size_t)(b * 2 + 1) * (H_ * W_);

    const int tid = threadIdx.y * 32 + threadIdx.x;

    // Stage 34x34 region of both frames, edge-clamped, coalesced along rows.
    for (int idx = tid; idx < TELEMS; idx += 256) {
        const int r = idx / TW_;
        const int c = idx - r * TW_;
        const int gy = min(max(ystart + r, 0), H_ - 1);
        const int gx = min(max(xstart + c, 0), W_ - 1);
        const int g = gy * W_ + gx;
        tile0[idx] = frame0[g];
        tile1[idx] = frame1[g];
    }
    __syncthreads();

    float* out0 = out + (size_t)((b * 2 + 0) * NT_ + t) * P_;
    float* out1 = out + (size_t)((b * 2 + 1) * NT_ + t) * P_;

    // lane = column j (0..30); lane 31 idle in compute
    const int j = threadIdx.x;
    if (j < WIN_) {
        // per-lane (column) quantities — computed once
        const float x  = basex + (float)j * step;
        const float fx = floorf(x);
        const float x0f = fminf(fmaxf(fx,        0.0f), (float)(W_ - 1));
        const float x1f = fminf(fmaxf(fx + 1.0f, 0.0f), (float)(W_ - 1));
        const float ax0 = x1f - x;      // weight factor for x0 column
        const float ax1 = x - x0f;      // weight factor for x1 column
        const int lx0 = (int)x0f - xstart;
        const int lx1 = (int)x1f - xstart;

        // rows: threadIdx.y + 8*k
        for (int i = threadIdx.y; i < WIN_; i += 8) {
            const float y  = basey + (float)i * step;
            const float fy = floorf(y);
            const float y0f = fminf(fmaxf(fy,        0.0f), (float)(H_ - 1));
            const float y1f = fminf(fmaxf(fy + 1.0f, 0.0f), (float)(H_ - 1));
            const float ay0 = y1f - y;
            const float ay1 = y - y0f;
            const int r0b = ((int)y0f - ystart) * TW_;
            const int r1b = ((int)y1f - ystart) * TW_;

            const float t0a = tile0[r0b + lx0];
            const float t0b = tile0[r0b + lx1];
            const float t0c = tile0[r1b + lx0];
            const float t0d = tile0[r1b + lx1];
            const float t1a = tile1[r0b + lx0];
            const float t1b = tile1[r0b + lx1];
            const float t1c = tile1[r1b + lx0];
            const float t1d = tile1[r1b + lx1];

            const float r0 = ay0 * (ax0 * t0a + ax1 * t0b) + ay1 * (ax0 * t0c + ax1 * t0d);
            const float r1 = ay0 * (ax0 * t1a + ax1 * t1b) + ay1 * (ax0 * t1c + ax1 * t1d);

            const int p = i * WIN_ + j;
            __builtin_nontemporal_store(r0, &out0[p]);
            __builtin_nontemporal_store(r1, &out1[p]);
        }
    }
}

extern "C" void kernel_launch(void* const* d_in, const int* in_sizes, int n_in,
                              void* d_out, int out_size, void* d_ws, size_t ws_size,
                              hipStream_t stream) {
    const float* track_locs = (const float*)d_in[0];   // (64, 128)
    const float* imgs       = (const float*)d_in[1];   // (64, 2, 512, 512, 1)
    float* out              = (float*)d_out;           // (64, 2, 64, 31, 31, 1)

    const int nblocks = B_ * NT_;   // 4096
    dim3 block(32, 8);
    motion_sample_kernel<<<nblocks, block, 0, stream>>>(track_locs, imgs, out);
}

// Round 4
// 183.285 us; speedup vs baseline: 1.0437x; 1.0055x over previous
//
#include <hip/hip_runtime.h>
#include <hip/hip_bf16.h>

// Problem constants (from reference)
#define B_     64
#define NT_    64
#define WIN_   31
#define P_     (WIN_ * WIN_)   // 961
#define H_     512
#define W_     512
#define TW_    40              // tile width: 16B-aligned origin + span 36 -> 40
#define TH_    34              // tile rows
#define TELEMS (TW_ * TH_)     // 1360

// out: (B, 2, NT, WIN, WIN, 1) float32
// imgs: (B, 2, H, W, 1) float32
// track_locs: (B, NT*2) float32

__global__ __launch_bounds__(256)
void motion_sample_kernel(const float* __restrict__ track_locs,
                          const float* __restrict__ imgs,
                          float* __restrict__ out) {
    // XCD swizzle: b = blk & 63 so all 64 tracks of a batch share blk%8
    // (same XCD under round-robin dispatch) -> L2 reuse of the batch region.
    const int blk = blockIdx.x;          // 0 .. B*NT-1
    const int b = blk & 63;
    const int t = blk >> 6;

    const float scale = (float)WIN_ / (float)W_;       // 31/512
    const float tx = track_locs[b * (NT_ * 2) + 2 * t];
    const float ty = track_locs[b * (NT_ * 2) + 2 * t + 1];

    const float halfwin = (float)WIN_ * 0.5f;          // 15.5
    const float basex = (-1.0f + tx / scale) * halfwin;
    const float basey = (-1.0f + ty / scale) * halfwin;
    const float step  = (2.0f / (float)(WIN_ - 1)) * halfwin;  // 31/30

    const int xstart = (int)floorf(basex);   // in [-16, 240]
    const int ystart = (int)floorf(basey);
    const int xal    = xstart & ~3;          // 16B-aligned tile origin (floor for negatives)

    __shared__ float tile0[TELEMS];
    __shared__ float tile1[TELEMS];

    const float* frame0 = imgs + (size_t)(b * 2 + 0) * (H_ * W_);
    const float* frame1 = imgs + (size_t)(b * 2 + 1) * (H_ * W_);

    const int tid = threadIdx.y * 32 + threadIdx.x;

    // cols needed: [x0i-xal, x1i-xal] subset of [0, 35] -> width 40 covers; rows [0,33].
    const bool interior = (xal >= 0) & (ystart >= 0);   // right/bottom never clip (xal<=240)

    if (interior) {
        // Vectorized staging: 10 float4 per row per frame; 680 float4 total.
        const int NV = TH_ * (TW_ / 4);     // 340 per frame
        for (int idx = tid; idx < 2 * NV; idx += 256) {
            const int fsel = idx >= NV;
            const int k = idx - fsel * NV;
            const int r = k / 10;
            const int c4 = k - r * 10;
            const float* fp = fsel ? frame1 : frame0;
            const float4 v = *((const float4*)(fp + (ystart + r) * W_ + xal) + c4);
            float* dst = (fsel ? tile1 : tile0) + r * TW_ + c4 * 4;
            *(float4*)dst = v;
        }
    } else {
        // Scalar clamped staging (block-uniform branch; ~13% of blocks).
        for (int idx = tid; idx < TELEMS; idx += 256) {
            const int r = idx / TW_;
            const int c = idx - r * TW_;
            const int gy = min(max(ystart + r, 0), H_ - 1);
            const int gx = min(max(xal + c, 0), W_ - 1);
            const int g = gy * W_ + gx;
            tile0[idx] = frame0[g];
            tile1[idx] = frame1[g];
        }
    }
    __syncthreads();

    float* out0 = out + (size_t)((b * 2 + 0) * NT_ + t) * P_;
    float* out1 = out + (size_t)((b * 2 + 1) * NT_ + t) * P_;

    // lane = column j (0..30); lane 31 idle in compute
    const int j = threadIdx.x;
    if (j < WIN_) {
        // per-lane (column) quantities — computed once
        const float x  = basex + (float)j * step;
        const float fx = floorf(x);
        const float x0f = fminf(fmaxf(fx,        0.0f), (float)(W_ - 1));
        const float x1f = fminf(fmaxf(fx + 1.0f, 0.0f), (float)(W_ - 1));
        const float ax0 = x1f - x;
        const float ax1 = x - x0f;
        const int lx0 = (int)x0f - xal;
        const int lx1 = (int)x1f - xal;

        for (int i = threadIdx.y; i < WIN_; i += 8) {
            const float y  = basey + (float)i * step;
            const float fy = floorf(y);
            const float y0f = fminf(fmaxf(fy,        0.0f), (float)(H_ - 1));
            const float y1f = fminf(fmaxf(fy + 1.0f, 0.0f), (float)(H_ - 1));
            const float ay0 = y1f - y;
            const float ay1 = y - y0f;
            const int r0b = ((int)y0f - ystart) * TW_;
            const int r1b = ((int)y1f - ystart) * TW_;

            const float t0a = tile0[r0b + lx0];
            const float t0b = tile0[r0b + lx1];
            const float t0c = tile0[r1b + lx0];
            const float t0d = tile0[r1b + lx1];
            const float t1a = tile1[r0b + lx0];
            const float t1b = tile1[r0b + lx1];
            const float t1c = tile1[r1b + lx0];
            const float t1d = tile1[r1b + lx1];

            const float r0 = ay0 * (ax0 * t0a + ax1 * t0b) + ay1 * (ax0 * t0c + ax1 * t0d);
            const float r1 = ay0 * (ax0 * t1a + ax1 * t1b) + ay1 * (ax0 * t1c + ax1 * t1d);

            const int p = i * WIN_ + j;
            __builtin_nontemporal_store(r0, &out0[p]);
            __builtin_nontemporal_store(r1, &out1[p]);
        }
    }
}

extern "C" void kernel_launch(void* const* d_in, const int* in_sizes, int n_in,
                              void* d_out, int out_size, void* d_ws, size_t ws_size,
                              hipStream_t stream) {
    const float* track_locs = (const float*)d_in[0];   // (64, 128)
    const float* imgs       = (const float*)d_in[1];   // (64, 2, 512, 512, 1)
    float* out              = (float*)d_out;           // (64, 2, 64, 31, 31, 1)

    const int nblocks = B_ * NT_;   // 4096
    dim3 block(32, 8);
    motion_sample_kernel<<<nblocks, block, 0, stream>>>(track_locs, imgs, out);
}